// Round 1
// baseline (698.815 us; speedup 1.0000x reference)
//
#include <hip/hip_runtime.h>
#include <hip/hip_bf16.h>

// Problem constants (fixed by the reference)
#define B_DIM 8192
#define K_DIM 4096
#define N_DIM 4096
#define GROUP 128
#define NG    (K_DIM / GROUP)   // 32 groups
#define INV_SQRT_GROUP 0.08838834764831845f  // 1/sqrt(128)

using bf16x8 = __attribute__((ext_vector_type(8))) short;  // 8 bf16 (4 VGPRs)
using f32x4  = __attribute__((ext_vector_type(4))) float;  // 4 fp32 acc

// round-to-nearest-even f32 -> bf16
__device__ inline unsigned short f2bf(float f) {
    union { float f; unsigned u; } v; v.f = f;
    unsigned r = v.u + 0x7fffu + ((v.u >> 16) & 1u);
    return (unsigned short)(r >> 16);
}

#define GLOAD_LDS16(gp, lp)                                                   \
    __builtin_amdgcn_global_load_lds(                                         \
        (__attribute__((address_space(1))) void*)(gp),                        \
        (__attribute__((address_space(3))) void*)(lp), 16, 0, 0)

// ---------------------------------------------------------------------------
// Kernel 1: cast x (B,K) f32 -> bf16, 8 elems/thread, 16B stores
// ---------------------------------------------------------------------------
__global__ __launch_bounds__(256) void cast_x_kernel(
    const float* __restrict__ x, unsigned short* __restrict__ xb, size_t n8)
{
    size_t i = (size_t)blockIdx.x * blockDim.x + threadIdx.x;
    if (i >= n8) return;
    const float4* xp = (const float4*)x;
    float4 a = xp[2 * i];
    float4 b = xp[2 * i + 1];
    union { unsigned short s[8]; uint4 v; } pk;
    pk.s[0] = f2bf(a.x); pk.s[1] = f2bf(a.y); pk.s[2] = f2bf(a.z); pk.s[3] = f2bf(a.w);
    pk.s[4] = f2bf(b.x); pk.s[5] = f2bf(b.y); pk.s[6] = f2bf(b.z); pk.s[7] = f2bf(b.w);
    ((uint4*)xb)[i] = pk.v;
}

// ---------------------------------------------------------------------------
// Kernel 2: V[n, g*128+k] = (norms[n,g]/sqrt(128)) * sum_j cb[idx[n,g*128+j]] * R[g,j,k]
// Per block: one group g, 128 n-rows. W' and R^T staged in LDS (bf16, padded),
// 128x128x128 MFMA matmul, V written as bf16.
// ---------------------------------------------------------------------------
__global__ __launch_bounds__(256) void prep_v_kernel(
    const int*   __restrict__ indices,   // (N, K)
    const float* __restrict__ codebook,  // (16,)
    const float* __restrict__ norms,     // (N, G)
    const float* __restrict__ rot,       // (G, 128, 128)
    unsigned short* __restrict__ Vout)   // (N, K) bf16
{
    const int g  = blockIdx.y;
    const int n0 = blockIdx.x * 128;
    const int tid = threadIdx.x;

    __shared__ __attribute__((aligned(16))) unsigned short w_lds[128][136];   // W'[nl][j], scaled
    __shared__ __attribute__((aligned(16))) unsigned short rt_lds[128][136];  // R^T: [k][j]
    __shared__ float s_lds[128];
    __shared__ float cb_lds[16];

    if (tid < 16)  cb_lds[tid] = codebook[tid];
    if (tid < 128) s_lds[tid] = norms[(size_t)(n0 + tid) * NG + g] * INV_SQRT_GROUP;
    __syncthreads();

    // dequant + scale W' -> LDS (coalesced over j)
    for (int e = tid; e < 128 * 128; e += 256) {
        int nl = e >> 7, j = e & 127;
        int q = indices[(size_t)(n0 + nl) * K_DIM + g * GROUP + j];
        w_lds[nl][j] = f2bf(cb_lds[q] * s_lds[nl]);
    }
    // stage R^T (read coalesced over k)
    const float* Rg = rot + (size_t)g * GROUP * GROUP;
    for (int e = tid; e < 128 * 128; e += 256) {
        int j = e >> 7, k = e & 127;
        rt_lds[k][j] = f2bf(Rg[j * 128 + k]);
    }
    __syncthreads();

    const int lane = tid & 63;
    const int wv   = tid >> 6;
    const int l15  = lane & 15;
    const int quad = lane >> 4;
    const int wn = (wv >> 1) * 64;   // n offset within tile
    const int wk = (wv & 1) * 64;    // k offset within tile

    f32x4 acc[4][4] = {};

    for (int js = 0; js < 4; ++js) {
        const int jo = js * 32 + quad * 8;
        bf16x8 aF[4], bF[4];
        for (int mi = 0; mi < 4; ++mi)
            aF[mi] = *(const bf16x8*)&w_lds[wn + mi * 16 + l15][jo];
        for (int ni = 0; ni < 4; ++ni)
            bF[ni] = *(const bf16x8*)&rt_lds[wk + ni * 16 + l15][jo];
        for (int mi = 0; mi < 4; ++mi)
            for (int ni = 0; ni < 4; ++ni)
                acc[mi][ni] = __builtin_amdgcn_mfma_f32_16x16x32_bf16(
                    aF[mi], bF[ni], acc[mi][ni], 0, 0, 0);
    }

    // C/D layout: row = quad*4 + r (n), col = l15 (k)
    for (int mi = 0; mi < 4; ++mi) {
        int n = n0 + wn + mi * 16 + quad * 4;
        for (int ni = 0; ni < 4; ++ni) {
            int k = wk + ni * 16 + l15;
            unsigned short* dst = Vout + (size_t)n * K_DIM + g * GROUP + k;
            for (int r = 0; r < 4; ++r)
                dst[(size_t)r * K_DIM] = f2bf(acc[mi][ni][r]);
        }
    }
}

// ---------------------------------------------------------------------------
// Kernel 3: C (8192x4096 f32) = Xb (8192x4096 bf16) @ V^T (V is 4096x4096 bf16)
// m97-style: 128x128 tile, BK=32, 4 waves (2x2 of 64x64), 4x4 accs/wave,
// global_load_lds width-16 staging.
// ---------------------------------------------------------------------------
__global__ __launch_bounds__(256) void gemm_bt_kernel(
    const unsigned short* __restrict__ A,   // (B_DIM, K_DIM) bf16
    const unsigned short* __restrict__ Bm,  // (N_DIM, K_DIM) bf16
    float* __restrict__ C)                  // (B_DIM, N_DIM) f32
{
    const int tid = threadIdx.x;
    const int n0 = blockIdx.x * 128;
    const int m0 = blockIdx.y * 128;

    __shared__ __attribute__((aligned(16))) unsigned short a_lds[128 * 32];
    __shared__ __attribute__((aligned(16))) unsigned short b_lds[128 * 32];

    const int lane = tid & 63;
    const int wv   = tid >> 6;
    const int l15  = lane & 15;
    const int quad = lane >> 4;
    const int wm = (wv >> 1) * 64;
    const int wn = (wv & 1) * 64;

    // staging: 512 chunks of 16B per tile; chunk c: row=c>>2, koff=(c&3)*8 elems
    const int c0  = tid;
    const int c1  = tid + 256;
    const int lb0 = (tid & ~63);        // wave-uniform lds chunk base, pass 0
    const int lb1 = (tid & ~63) + 256;  // pass 1

    const int r0 = c0 >> 2, ko0 = (c0 & 3) * 8;
    const int r1 = c1 >> 2, ko1 = (c1 & 3) * 8;

    f32x4 acc[4][4] = {};

    for (int kt = 0; kt < K_DIM / 32; ++kt) {
        const int k0 = kt * 32;
        GLOAD_LDS16(A  + (size_t)(m0 + r0) * K_DIM + k0 + ko0, a_lds + lb0 * 8);
        GLOAD_LDS16(A  + (size_t)(m0 + r1) * K_DIM + k0 + ko1, a_lds + lb1 * 8);
        GLOAD_LDS16(Bm + (size_t)(n0 + r0) * K_DIM + k0 + ko0, b_lds + lb0 * 8);
        GLOAD_LDS16(Bm + (size_t)(n0 + r1) * K_DIM + k0 + ko1, b_lds + lb1 * 8);
        __syncthreads();

        const int ko = quad * 8;
        bf16x8 aF[4], bF[4];
        for (int mi = 0; mi < 4; ++mi)
            aF[mi] = *(const bf16x8*)&a_lds[(wm + mi * 16 + l15) * 32 + ko];
        for (int ni = 0; ni < 4; ++ni)
            bF[ni] = *(const bf16x8*)&b_lds[(wn + ni * 16 + l15) * 32 + ko];
        for (int mi = 0; mi < 4; ++mi)
            for (int ni = 0; ni < 4; ++ni)
                acc[mi][ni] = __builtin_amdgcn_mfma_f32_16x16x32_bf16(
                    aF[mi], bF[ni], acc[mi][ni], 0, 0, 0);
        __syncthreads();
    }

    // epilogue: row = quad*4 + r (m), col = l15 (n)
    for (int mi = 0; mi < 4; ++mi) {
        int m = m0 + wm + mi * 16 + quad * 4;
        for (int ni = 0; ni < 4; ++ni) {
            int n = n0 + wn + ni * 16 + l15;
            float* dst = C + (size_t)m * N_DIM + n;
            for (int r = 0; r < 4; ++r)
                dst[(size_t)r * N_DIM] = acc[mi][ni][r];
        }
    }
}

// ---------------------------------------------------------------------------
extern "C" void kernel_launch(void* const* d_in, const int* in_sizes, int n_in,
                              void* d_out, int out_size, void* d_ws, size_t ws_size,
                              hipStream_t stream)
{
    const float* x        = (const float*)d_in[0];  // (B, K)
    const int*   indices  = (const int*)d_in[1];    // (N, K)
    const float* codebook = (const float*)d_in[2];  // (16,)
    const float* norms    = (const float*)d_in[3];  // (N, G)
    const float* rot      = (const float*)d_in[4];  // (G, 128, 128)
    float* out            = (float*)d_out;          // (B, N)

    unsigned short* Xb = (unsigned short*)d_ws;                       // B*K bf16 = 64 MiB
    unsigned short* V  = Xb + (size_t)B_DIM * K_DIM;                  // N*K bf16 = 32 MiB

    // 1) cast x to bf16
    {
        size_t n8 = (size_t)B_DIM * K_DIM / 8;
        cast_x_kernel<<<dim3((unsigned)(n8 / 256)), dim3(256), 0, stream>>>(x, Xb, n8);
    }
    // 2) build rotated/dequantized weights V
    {
        dim3 grid(N_DIM / 128, NG);
        prep_v_kernel<<<grid, dim3(256), 0, stream>>>(indices, codebook, norms, rot, V);
    }
    // 3) out = Xb @ V^T
    {
        dim3 grid(N_DIM / 128, B_DIM / 128);
        gemm_bt_kernel<<<grid, dim3(256), 0, stream>>>(Xb, V, out);
    }
}

// Round 2
// 683.728 us; speedup vs baseline: 1.0221x; 1.0221x over previous
//
#include <hip/hip_runtime.h>
#include <hip/hip_bf16.h>

// Problem constants (fixed by the reference)
#define B_DIM 8192
#define K_DIM 4096
#define N_DIM 4096
#define GROUP 128
#define NG    (K_DIM / GROUP)   // 32 groups
#define INV_SQRT_GROUP 0.08838834764831845f  // 1/sqrt(128)

using bf16x8 = __attribute__((ext_vector_type(8))) short;  // 8 bf16 (4 VGPRs)
using f32x4  = __attribute__((ext_vector_type(4))) float;  // 4 fp32 acc

// round-to-nearest-even f32 -> bf16
__device__ inline unsigned short f2bf(float f) {
    union { float f; unsigned u; } v; v.f = f;
    unsigned r = v.u + 0x7fffu + ((v.u >> 16) & 1u);
    return (unsigned short)(r >> 16);
}

#define GLOAD_LDS16(gp, lp)                                                   \
    __builtin_amdgcn_global_load_lds(                                         \
        (__attribute__((address_space(1))) void*)(gp),                        \
        (__attribute__((address_space(3))) void*)(lp), 16, 0, 0)

// ---------------------------------------------------------------------------
// Kernel 1: cast x (B,K) f32 -> bf16, 8 elems/thread, 16B stores
// ---------------------------------------------------------------------------
__global__ __launch_bounds__(256) void cast_x_kernel(
    const float* __restrict__ x, unsigned short* __restrict__ xb, size_t n8)
{
    size_t i = (size_t)blockIdx.x * blockDim.x + threadIdx.x;
    if (i >= n8) return;
    const float4* xp = (const float4*)x;
    float4 a = xp[2 * i];
    float4 b = xp[2 * i + 1];
    union { unsigned short s[8]; uint4 v; } pk;
    pk.s[0] = f2bf(a.x); pk.s[1] = f2bf(a.y); pk.s[2] = f2bf(a.z); pk.s[3] = f2bf(a.w);
    pk.s[4] = f2bf(b.x); pk.s[5] = f2bf(b.y); pk.s[6] = f2bf(b.z); pk.s[7] = f2bf(b.w);
    ((uint4*)xb)[i] = pk.v;
}

// ---------------------------------------------------------------------------
// Kernel 2: V[n, g*128+k] = (norms[n,g]/sqrt(128)) * sum_j cb[idx[n,g*128+j]] * R[g,j,k]
// Per block: one group g, 128 n-rows. W' staged in LDS (bf16, +8 pad -> bank
// stride 4 -> conflict-free b128 fragment reads). R^T B-fragments loaded
// directly from global (16 consecutive lanes = 64 contiguous bytes; R_g is
// 64 KB and L2-resident across the 32 blocks of this group).
// ---------------------------------------------------------------------------
__global__ __launch_bounds__(256) void prep_v_kernel(
    const int*   __restrict__ indices,   // (N, K)
    const float* __restrict__ codebook,  // (16,)
    const float* __restrict__ norms,     // (N, G)
    const float* __restrict__ rot,       // (G, 128, 128)
    unsigned short* __restrict__ Vout)   // (N, K) bf16
{
    const int g  = blockIdx.y;
    const int n0 = blockIdx.x * 128;
    const int tid = threadIdx.x;

    __shared__ __attribute__((aligned(16))) unsigned short w_lds[128][136];
    __shared__ float s_lds[128];
    __shared__ float cb_lds[16];

    if (tid < 16)  cb_lds[tid] = codebook[tid];
    if (tid < 128) s_lds[tid] = norms[(size_t)(n0 + tid) * NG + g] * INV_SQRT_GROUP;
    __syncthreads();

    // dequant + scale W' -> LDS: each thread does 8 chunks of 8 indices
    // (two int4 loads = 32B coalesced), packs 8 bf16, one 16B LDS store.
    for (int e = tid; e < 128 * 16; e += 256) {
        const int nl = e >> 4, jc = e & 15;
        const float s = s_lds[nl];
        const int4* ip = (const int4*)(indices + (size_t)(n0 + nl) * K_DIM + g * GROUP + jc * 8);
        int4 i0 = ip[0];
        int4 i1 = ip[1];
        union { unsigned short h[8]; uint4 v; } pk;
        pk.h[0] = f2bf(cb_lds[i0.x] * s); pk.h[1] = f2bf(cb_lds[i0.y] * s);
        pk.h[2] = f2bf(cb_lds[i0.z] * s); pk.h[3] = f2bf(cb_lds[i0.w] * s);
        pk.h[4] = f2bf(cb_lds[i1.x] * s); pk.h[5] = f2bf(cb_lds[i1.y] * s);
        pk.h[6] = f2bf(cb_lds[i1.z] * s); pk.h[7] = f2bf(cb_lds[i1.w] * s);
        *(uint4*)&w_lds[nl][jc * 8] = pk.v;
    }
    __syncthreads();

    const int lane = tid & 63;
    const int wv   = tid >> 6;
    const int l15  = lane & 15;
    const int quad = lane >> 4;
    const int wn = (wv >> 1) * 64;   // n offset within tile
    const int wk = (wv & 1) * 64;    // k offset within tile

    const float* Rg = rot + (size_t)g * GROUP * GROUP;

    f32x4 acc[4][4] = {};

    for (int js = 0; js < 4; ++js) {
        const int jo = js * 32 + quad * 8;
        bf16x8 aF[4], bF[4];
        for (int mi = 0; mi < 4; ++mi)
            aF[mi] = *(const bf16x8*)&w_lds[wn + mi * 16 + l15][jo];
        for (int ni = 0; ni < 4; ++ni) {
            const int k = wk + ni * 16 + l15;
            union { unsigned short h[8]; bf16x8 v; } pk;
            for (int jj = 0; jj < 8; ++jj)
                pk.h[jj] = f2bf(Rg[(size_t)(jo + jj) * 128 + k]);
            bF[ni] = pk.v;
        }
        for (int mi = 0; mi < 4; ++mi)
            for (int ni = 0; ni < 4; ++ni)
                acc[mi][ni] = __builtin_amdgcn_mfma_f32_16x16x32_bf16(
                    aF[mi], bF[ni], acc[mi][ni], 0, 0, 0);
    }

    // C/D layout: row = quad*4 + r (n), col = l15 (k)
    for (int mi = 0; mi < 4; ++mi) {
        int n = n0 + wn + mi * 16 + quad * 4;
        for (int ni = 0; ni < 4; ++ni) {
            int k = wk + ni * 16 + l15;
            unsigned short* dst = Vout + (size_t)n * K_DIM + g * GROUP + k;
            for (int r = 0; r < 4; ++r)
                dst[(size_t)r * K_DIM] = f2bf(acc[mi][ni][r]);
        }
    }
}

// ---------------------------------------------------------------------------
// Kernel 3: C (8192x4096 f32) = Xb (8192x4096 bf16) @ V^T (V is 4096x4096 bf16)
// m97-style: 128x128 tile, BK=32, 4 waves (2x2 of 64x64), 4x4 accs/wave,
// global_load_lds width-16 staging.
// XOR chunk swizzle: global_load_lds forces LDS dest = lane*16B, so we
// permute the SOURCE: slot c holds logical 16B chunk (c&3)^((c>>3)&3) of
// row c>>2; fragment reads use physical chunk quad^((row>>1)&3). This
// spreads fragment reads over all 8 bank groups (was 2 -> SQ_LDS_BANK_CONFLICT).
// ---------------------------------------------------------------------------
__global__ __launch_bounds__(256) void gemm_bt_kernel(
    const unsigned short* __restrict__ A,   // (B_DIM, K_DIM) bf16
    const unsigned short* __restrict__ Bm,  // (N_DIM, K_DIM) bf16
    float* __restrict__ C)                  // (B_DIM, N_DIM) f32
{
    const int tid = threadIdx.x;
    const int n0 = blockIdx.x * 128;
    const int m0 = blockIdx.y * 128;

    __shared__ __attribute__((aligned(16))) unsigned short a_lds[128 * 32];
    __shared__ __attribute__((aligned(16))) unsigned short b_lds[128 * 32];

    const int lane = tid & 63;
    const int wv   = tid >> 6;
    const int l15  = lane & 15;
    const int quad = lane >> 4;
    const int wm = (wv >> 1) * 64;
    const int wn = (wv & 1) * 64;

    // staging: 512 chunks of 16B per tile; physical slot c: row=c>>2,
    // swizzled source chunk = (c&3)^((c>>3)&3)
    const int c0  = tid;
    const int c1  = tid + 256;
    const int lb0 = (tid & ~63);        // wave-uniform lds chunk base, pass 0
    const int lb1 = (tid & ~63) + 256;  // pass 1

    const int r0 = c0 >> 2, ko0 = (((c0 & 3) ^ ((c0 >> 3) & 3))) * 8;
    const int r1 = c1 >> 2, ko1 = (((c1 & 3) ^ ((c1 >> 3) & 3))) * 8;

    // fragment-read physical chunk offset (elems): logical chunk = quad
    const int ko = ((quad ^ ((l15 >> 1) & 3))) * 8;

    f32x4 acc[4][4] = {};

    for (int kt = 0; kt < K_DIM / 32; ++kt) {
        const int k0 = kt * 32;
        GLOAD_LDS16(A  + (size_t)(m0 + r0) * K_DIM + k0 + ko0, a_lds + lb0 * 8);
        GLOAD_LDS16(A  + (size_t)(m0 + r1) * K_DIM + k0 + ko1, a_lds + lb1 * 8);
        GLOAD_LDS16(Bm + (size_t)(n0 + r0) * K_DIM + k0 + ko0, b_lds + lb0 * 8);
        GLOAD_LDS16(Bm + (size_t)(n0 + r1) * K_DIM + k0 + ko1, b_lds + lb1 * 8);
        __syncthreads();

        bf16x8 aF[4], bF[4];
        for (int mi = 0; mi < 4; ++mi)
            aF[mi] = *(const bf16x8*)&a_lds[(wm + mi * 16 + l15) * 32 + ko];
        for (int ni = 0; ni < 4; ++ni)
            bF[ni] = *(const bf16x8*)&b_lds[(wn + ni * 16 + l15) * 32 + ko];
        for (int mi = 0; mi < 4; ++mi)
            for (int ni = 0; ni < 4; ++ni)
                acc[mi][ni] = __builtin_amdgcn_mfma_f32_16x16x32_bf16(
                    aF[mi], bF[ni], acc[mi][ni], 0, 0, 0);
        __syncthreads();
    }

    // epilogue: row = quad*4 + r (m), col = l15 (n)
    for (int mi = 0; mi < 4; ++mi) {
        int m = m0 + wm + mi * 16 + quad * 4;
        for (int ni = 0; ni < 4; ++ni) {
            int n = n0 + wn + ni * 16 + l15;
            float* dst = C + (size_t)m * N_DIM + n;
            for (int r = 0; r < 4; ++r)
                dst[(size_t)r * N_DIM] = acc[mi][ni][r];
        }
    }
}

// ---------------------------------------------------------------------------
extern "C" void kernel_launch(void* const* d_in, const int* in_sizes, int n_in,
                              void* d_out, int out_size, void* d_ws, size_t ws_size,
                              hipStream_t stream)
{
    const float* x        = (const float*)d_in[0];  // (B, K)
    const int*   indices  = (const int*)d_in[1];    // (N, K)
    const float* codebook = (const float*)d_in[2];  // (16,)
    const float* norms    = (const float*)d_in[3];  // (N, G)
    const float* rot      = (const float*)d_in[4];  // (G, 128, 128)
    float* out            = (float*)d_out;          // (B, N)

    unsigned short* Xb = (unsigned short*)d_ws;                       // B*K bf16 = 64 MiB
    unsigned short* V  = Xb + (size_t)B_DIM * K_DIM;                  // N*K bf16 = 32 MiB

    // 1) cast x to bf16
    {
        size_t n8 = (size_t)B_DIM * K_DIM / 8;
        cast_x_kernel<<<dim3((unsigned)(n8 / 256)), dim3(256), 0, stream>>>(x, Xb, n8);
    }
    // 2) build rotated/dequantized weights V
    {
        dim3 grid(N_DIM / 128, NG);
        prep_v_kernel<<<grid, dim3(256), 0, stream>>>(indices, codebook, norms, rot, V);
    }
    // 3) out = Xb @ V^T
    {
        dim3 grid(N_DIM / 128, B_DIM / 128);
        gemm_bt_kernel<<<grid, dim3(256), 0, stream>>>(Xb, V, out);
    }
}

// Round 4
// 652.496 us; speedup vs baseline: 1.0710x; 1.0479x over previous
//
#include <hip/hip_runtime.h>
#include <hip/hip_bf16.h>

// Problem constants (fixed by the reference)
#define B_DIM 8192
#define K_DIM 4096
#define N_DIM 4096
#define GROUP 128
#define NG    (K_DIM / GROUP)   // 32 groups
#define INV_SQRT_GROUP 0.08838834764831845f  // 1/sqrt(128)

using bf16x8 = __attribute__((ext_vector_type(8))) short;  // 8 bf16 (4 VGPRs)
using f32x4  = __attribute__((ext_vector_type(4))) float;  // 4 fp32 acc

// round-to-nearest-even f32 -> bf16
__device__ inline unsigned short f2bf(float f) {
    union { float f; unsigned u; } v; v.f = f;
    unsigned r = v.u + 0x7fffu + ((v.u >> 16) & 1u);
    return (unsigned short)(r >> 16);
}

#define GLOAD_LDS16(gp, lp)                                                   \
    __builtin_amdgcn_global_load_lds(                                         \
        (__attribute__((address_space(1))) void*)(gp),                        \
        (__attribute__((address_space(3))) void*)(lp), 16, 0, 0)

// ---------------------------------------------------------------------------
// Kernel 1: cast x (B,K) f32 -> bf16, 8 elems/thread, 16B stores
// ---------------------------------------------------------------------------
__global__ __launch_bounds__(256) void cast_x_kernel(
    const float* __restrict__ x, unsigned short* __restrict__ xb, size_t n8)
{
    size_t i = (size_t)blockIdx.x * blockDim.x + threadIdx.x;
    if (i >= n8) return;
    const float4* xp = (const float4*)x;
    float4 a = xp[2 * i];
    float4 b = xp[2 * i + 1];
    union { unsigned short s[8]; uint4 v; } pk;
    pk.s[0] = f2bf(a.x); pk.s[1] = f2bf(a.y); pk.s[2] = f2bf(a.z); pk.s[3] = f2bf(a.w);
    pk.s[4] = f2bf(b.x); pk.s[5] = f2bf(b.y); pk.s[6] = f2bf(b.z); pk.s[7] = f2bf(b.w);
    ((uint4*)xb)[i] = pk.v;
}

// ---------------------------------------------------------------------------
// Kernel 1b: Rt[g][k][j] = bf16(R[g][j][k])  (1 MiB out; reads coalesced over k)
// ---------------------------------------------------------------------------
__global__ __launch_bounds__(256) void cast_rot_kernel(
    const float* __restrict__ rot, unsigned short* __restrict__ Rt)
{
    const int g = blockIdx.x;
    const float* Rg = rot + (size_t)g * GROUP * GROUP;
    unsigned short* Rtg = Rt + (size_t)g * GROUP * GROUP;
    for (int e = threadIdx.x; e < 128 * 32; e += 256) {
        int j = e >> 5, kc = (e & 31) * 4;
        float4 v = *(const float4*)(Rg + (size_t)j * 128 + kc);
        Rtg[(size_t)(kc + 0) * 128 + j] = f2bf(v.x);
        Rtg[(size_t)(kc + 1) * 128 + j] = f2bf(v.y);
        Rtg[(size_t)(kc + 2) * 128 + j] = f2bf(v.z);
        Rtg[(size_t)(kc + 3) * 128 + j] = f2bf(v.w);
    }
}

// ---------------------------------------------------------------------------
// Kernel 2: V[n, g*128+k] = (norms[n,g]/sqrt(128)) * sum_j cb[idx[n,g*128+j]] * R[g,j,k]
// W' staged in LDS (bf16, +8 pad). R^T B-fragments are single 16B vector
// loads from the pre-cast Rt (k-major bf16, L2-resident 32 KB per group).
// ---------------------------------------------------------------------------
__global__ __launch_bounds__(256) void prep_v_kernel(
    const int*   __restrict__ indices,   // (N, K)
    const float* __restrict__ codebook,  // (16,)
    const float* __restrict__ norms,     // (N, G)
    const unsigned short* __restrict__ Rt, // (G, 128, 128) bf16, k-major
    unsigned short* __restrict__ Vout)   // (N, K) bf16
{
    const int g  = blockIdx.y;
    const int n0 = blockIdx.x * 128;
    const int tid = threadIdx.x;

    __shared__ __attribute__((aligned(16))) unsigned short w_lds[128][136];
    __shared__ float s_lds[128];
    __shared__ float cb_lds[16];

    if (tid < 16)  cb_lds[tid] = codebook[tid];
    if (tid < 128) s_lds[tid] = norms[(size_t)(n0 + tid) * NG + g] * INV_SQRT_GROUP;
    __syncthreads();

    for (int e = tid; e < 128 * 16; e += 256) {
        const int nl = e >> 4, jc = e & 15;
        const float s = s_lds[nl];
        const int4* ip = (const int4*)(indices + (size_t)(n0 + nl) * K_DIM + g * GROUP + jc * 8);
        int4 i0 = ip[0];
        int4 i1 = ip[1];
        union { unsigned short h[8]; uint4 v; } pk;
        pk.h[0] = f2bf(cb_lds[i0.x] * s); pk.h[1] = f2bf(cb_lds[i0.y] * s);
        pk.h[2] = f2bf(cb_lds[i0.z] * s); pk.h[3] = f2bf(cb_lds[i0.w] * s);
        pk.h[4] = f2bf(cb_lds[i1.x] * s); pk.h[5] = f2bf(cb_lds[i1.y] * s);
        pk.h[6] = f2bf(cb_lds[i1.z] * s); pk.h[7] = f2bf(cb_lds[i1.w] * s);
        *(uint4*)&w_lds[nl][jc * 8] = pk.v;
    }
    __syncthreads();

    const int lane = tid & 63;
    const int wv   = tid >> 6;
    const int l15  = lane & 15;
    const int quad = lane >> 4;
    const int wn = (wv >> 1) * 64;   // n offset within tile
    const int wk = (wv & 1) * 64;    // k offset within tile

    const unsigned short* Rtg = Rt + (size_t)g * GROUP * GROUP;

    f32x4 acc[4][4] = {};

    for (int js = 0; js < 4; ++js) {
        const int jo = js * 32 + quad * 8;
        bf16x8 aF[4], bF[4];
        for (int mi = 0; mi < 4; ++mi)
            aF[mi] = *(const bf16x8*)&w_lds[wn + mi * 16 + l15][jo];
        for (int ni = 0; ni < 4; ++ni) {
            const int k = wk + ni * 16 + l15;
            bF[ni] = *(const bf16x8*)(Rtg + (size_t)k * 128 + jo);
        }
        for (int mi = 0; mi < 4; ++mi)
            for (int ni = 0; ni < 4; ++ni)
                acc[mi][ni] = __builtin_amdgcn_mfma_f32_16x16x32_bf16(
                    aF[mi], bF[ni], acc[mi][ni], 0, 0, 0);
    }

    // C/D layout: row = quad*4 + r (n), col = l15 (k)
    for (int mi = 0; mi < 4; ++mi) {
        int n = n0 + wn + mi * 16 + quad * 4;
        for (int ni = 0; ni < 4; ++ni) {
            int k = wk + ni * 16 + l15;
            unsigned short* dst = Vout + (size_t)n * K_DIM + g * GROUP + k;
            for (int r = 0; r < 4; ++r)
                dst[(size_t)r * K_DIM] = f2bf(acc[mi][ni][r]);
        }
    }
}

// ---------------------------------------------------------------------------
// Kernel 3: C (8192x4096 f32) = Xb (8192x4096 bf16) @ V^T (V is 4096x4096 bf16)
// 128x128 tile, BK=64 (2x MFMA work per barrier vs BK=32), 4 waves, 4x4 accs,
// global_load_lds width-16 staging. LDS 32 KiB -> ~5 blocks/CU.
// XOR chunk swizzle: row has 8 16B-chunks; phys chunk = logical ^ (row&7).
// NOTE: phys chunk offset encodes the k-half already — do NOT add +32
// for the second half (that was R3's bug).
// ---------------------------------------------------------------------------
__global__ __launch_bounds__(256) void gemm_bt_kernel(
    const unsigned short* __restrict__ A,   // (B_DIM, K_DIM) bf16
    const unsigned short* __restrict__ Bm,  // (N_DIM, K_DIM) bf16
    float* __restrict__ C)                  // (B_DIM, N_DIM) f32
{
    const int tid = threadIdx.x;
    const int n0 = blockIdx.x * 128;
    const int m0 = blockIdx.y * 128;

    __shared__ __attribute__((aligned(16))) unsigned short a_lds[128 * 64];
    __shared__ __attribute__((aligned(16))) unsigned short b_lds[128 * 64];

    const int lane = tid & 63;
    const int wv   = tid >> 6;
    const int l15  = lane & 15;
    const int quad = lane >> 4;
    const int wm = (wv >> 1) * 64;
    const int wn = (wv & 1) * 64;

    // staging: 1024 chunks of 16B per operand, 4 passes of 256 threads.
    // physical slot c holds logical chunk (c&7)^((c>>3)&7) of row c>>3.
    int rr[4], ko[4], lb[4];
    for (int p = 0; p < 4; ++p) {
        int c = tid + 256 * p;
        rr[p] = c >> 3;
        ko[p] = ((c & 7) ^ (rr[p] & 7)) * 8;
        lb[p] = (tid & ~63) + 256 * p;   // wave-uniform dest chunk base
    }

    // fragment-read physical chunk offsets (elems): logical chunk h*4+quad,
    // phys = logical ^ (row&7) = logical ^ (l15&7)
    const int l7 = l15 & 7;
    const int koh0 = ((0 * 4 + quad) ^ l7) * 8;
    const int koh1 = ((1 * 4 + quad) ^ l7) * 8;

    f32x4 acc[4][4] = {};

    for (int kt = 0; kt < K_DIM / 64; ++kt) {
        const int k0 = kt * 64;
        for (int p = 0; p < 4; ++p) {
            GLOAD_LDS16(A  + (size_t)(m0 + rr[p]) * K_DIM + k0 + ko[p], a_lds + lb[p] * 8);
            GLOAD_LDS16(Bm + (size_t)(n0 + rr[p]) * K_DIM + k0 + ko[p], b_lds + lb[p] * 8);
        }
        __syncthreads();

        {
            bf16x8 aF[4], bF[4];
            for (int mi = 0; mi < 4; ++mi)
                aF[mi] = *(const bf16x8*)&a_lds[(wm + mi * 16 + l15) * 64 + koh0];
            for (int ni = 0; ni < 4; ++ni)
                bF[ni] = *(const bf16x8*)&b_lds[(wn + ni * 16 + l15) * 64 + koh0];
            for (int mi = 0; mi < 4; ++mi)
                for (int ni = 0; ni < 4; ++ni)
                    acc[mi][ni] = __builtin_amdgcn_mfma_f32_16x16x32_bf16(
                        aF[mi], bF[ni], acc[mi][ni], 0, 0, 0);
        }
        {
            bf16x8 aF[4], bF[4];
            for (int mi = 0; mi < 4; ++mi)
                aF[mi] = *(const bf16x8*)&a_lds[(wm + mi * 16 + l15) * 64 + koh1];
            for (int ni = 0; ni < 4; ++ni)
                bF[ni] = *(const bf16x8*)&b_lds[(wn + ni * 16 + l15) * 64 + koh1];
            for (int mi = 0; mi < 4; ++mi)
                for (int ni = 0; ni < 4; ++ni)
                    acc[mi][ni] = __builtin_amdgcn_mfma_f32_16x16x32_bf16(
                        aF[mi], bF[ni], acc[mi][ni], 0, 0, 0);
        }
        __syncthreads();
    }

    // epilogue: row = quad*4 + r (m), col = l15 (n)
    for (int mi = 0; mi < 4; ++mi) {
        int m = m0 + wm + mi * 16 + quad * 4;
        for (int ni = 0; ni < 4; ++ni) {
            int n = n0 + wn + ni * 16 + l15;
            float* dst = C + (size_t)m * N_DIM + n;
            for (int r = 0; r < 4; ++r)
                dst[(size_t)r * N_DIM] = acc[mi][ni][r];
        }
    }
}

// ---------------------------------------------------------------------------
extern "C" void kernel_launch(void* const* d_in, const int* in_sizes, int n_in,
                              void* d_out, int out_size, void* d_ws, size_t ws_size,
                              hipStream_t stream)
{
    const float* x        = (const float*)d_in[0];  // (B, K)
    const int*   indices  = (const int*)d_in[1];    // (N, K)
    const float* codebook = (const float*)d_in[2];  // (16,)
    const float* norms    = (const float*)d_in[3];  // (N, G)
    const float* rot      = (const float*)d_in[4];  // (G, 128, 128)
    float* out            = (float*)d_out;          // (B, N)

    unsigned short* Rt = (unsigned short*)d_ws;                       // 1 MiB
    unsigned short* Xb = Rt + (size_t)NG * GROUP * GROUP;             // 64 MiB
    unsigned short* V  = Xb + (size_t)B_DIM * K_DIM;                  // 32 MiB

    // 1) cast x to bf16; cast+transpose rotations to bf16
    {
        size_t n8 = (size_t)B_DIM * K_DIM / 8;
        cast_x_kernel<<<dim3((unsigned)(n8 / 256)), dim3(256), 0, stream>>>(x, Xb, n8);
        cast_rot_kernel<<<dim3(NG), dim3(256), 0, stream>>>(rot, Rt);
    }
    // 2) build rotated/dequantized weights V
    {
        dim3 grid(N_DIM / 128, NG);
        prep_v_kernel<<<grid, dim3(256), 0, stream>>>(indices, codebook, norms, Rt, V);
    }
    // 3) out = Xb @ V^T
    {
        dim3 grid(N_DIM / 128, B_DIM / 128);
        gemm_bt_kernel<<<grid, dim3(256), 0, stream>>>(Xb, V, out);
    }
}